// Round 23
// baseline (152.380 us; speedup 1.0000x reference)
//
#include <hip/hip_runtime.h>

typedef _Float16 f16x8 __attribute__((ext_vector_type(8)));
typedef unsigned short ushort8 __attribute__((ext_vector_type(8)));
typedef float f32x4 __attribute__((ext_vector_type(4)));

#define C_IN     256
#define C_OUT    512
#define M_PTS    25000
#define KNN      16
#define P_BLK    4
#define ROWS     (P_BLK * KNN)   /* 64 */
#define ROWB     528             /* padded row stride in bytes (264 f16), 16B-aligned */
#define NTHREADS 256

#define MFMA16(a, b, c) __builtin_amdgcn_mfma_f32_16x16x32_f16(a, b, c, 0, 0, 0)

__device__ __forceinline__ unsigned short f2h(float f) {
    _Float16 h = (_Float16)f;
    return __builtin_bit_cast(unsigned short, h);
}

// Pack W [C_IN][C_OUT] f32 -> f16 in MFMA B-fragment order (verified):
// Wp[nt*4096 + kk*512 + lane*8 + j] = W[(kk*32 + (lane>>4)*8 + j)*C_OUT + nt*16 + (lane&15)]
__global__ void pack_w_kernel(const float* __restrict__ W, unsigned short* __restrict__ Wp) {
    int t = blockIdx.x * blockDim.x + threadIdx.x;   // 0 .. 131071
    int j    = t & 7;
    int lane = (t >> 3) & 63;
    int kk   = (t >> 9) & 7;
    int nt   = t >> 12;                               // 0..31
    int k = kk * 32 + ((lane >> 4) << 3) + j;
    int n = nt * 16 + (lane & 15);
    Wp[t] = f2h(W[k * C_OUT + n]);
}

// CHAMPION (R17 == R21, passed twice: 152.4/151.4us, absmax 0.03125).
// Fingerprint: VGPR 60, MfmaUtil 28.5, VALUBusy 32.6, occ 39%, conflicts 1.44e7.
// 22 rounds established this as the hipcc-safe optimum: every restructuring
// (B-residency, kk-outer, wave=point, precompute, occupancy x2, 32x32 MFMA)
// was either resunk by the compiler (perf-neutral), HBM-bound, or silently
// corrupted by regalloc (the 0.12-0.19 absmax band). No deltas.
__global__ __launch_bounds__(NTHREADS, 4)
void fused_gather_ln_gemm_max(const float* __restrict__ x,
                              const int* __restrict__ idx,
                              const float* __restrict__ gamma,
                              const float* __restrict__ beta,
                              const unsigned short* __restrict__ Wp,
                              const float* __restrict__ bias,
                              float* __restrict__ out) {
    __shared__ char Ab[ROWS * ROWB];   // 33 KiB, f16 A-tile, padded rows, NO swizzle

    const int tid  = threadIdx.x;
    const int lane = tid & 63;
    const int wave = tid >> 6;
    const int m0   = blockIdx.x * P_BLK;

    // ---- Phase 1: gather + LayerNorm -> LDS (f16) ----
    float gm[16], bt[16];
    const int cg = (tid & 15) * 16;
    #pragma unroll
    for (int q = 0; q < 4; ++q) {
        float4 g4 = ((const float4*)(gamma + cg))[q];
        float4 b4 = ((const float4*)(beta  + cg))[q];
        gm[4*q+0] = g4.x; gm[4*q+1] = g4.y; gm[4*q+2] = g4.z; gm[4*q+3] = g4.w;
        bt[4*q+0] = b4.x; bt[4*q+1] = b4.y; bt[4*q+2] = b4.z; bt[4*q+3] = b4.w;
    }
    #pragma unroll
    for (int it = 0; it < ROWS / 16; ++it) {
        const int r  = it * 16 + (tid >> 4);
        const int xr = idx[m0 * KNN + r];
        const float4* xp = (const float4*)(x + (size_t)xr * C_IN) + (tid & 15) * 4;
        float vv[16];
        float s = 0.f, sq = 0.f;
        #pragma unroll
        for (int q = 0; q < 4; ++q) {
            float4 v4 = xp[q];
            vv[4*q+0] = v4.x; vv[4*q+1] = v4.y; vv[4*q+2] = v4.z; vv[4*q+3] = v4.w;
        }
        #pragma unroll
        for (int e = 0; e < 16; ++e) { s += vv[e]; sq += vv[e]*vv[e]; }
        #pragma unroll
        for (int o = 1; o < 16; o <<= 1) {
            s  += __shfl_xor(s, o);
            sq += __shfl_xor(sq, o);
        }
        const float mu  = s * (1.0f/256.0f);
        const float var = sq * (1.0f/256.0f) - mu * mu;
        const float rs  = rsqrtf(var + 1e-5f);
        ushort8 c0, c1;
        #pragma unroll
        for (int e = 0; e < 8; ++e) c0[e] = f2h((vv[e]   - mu)*rs*gm[e]   + bt[e]);
        #pragma unroll
        for (int e = 0; e < 8; ++e) c1[e] = f2h((vv[e+8] - mu)*rs*gm[e+8] + bt[e+8]);
        const int cb = (tid & 15) * 32;
        *(ushort8*)(Ab + r*ROWB + cb)      = c0;
        *(ushort8*)(Ab + r*ROWB + cb + 16) = c1;
    }
    __syncthreads();

    // ---- Phase 2: kk-outer, 2-point chunks (low pressure: 2B + 2A + 4 acc live) ----
    const int csub = (lane >> 4) << 4;
    const int rlo  = lane & 15;

    #pragma unroll 1
    for (int ntp = 0; ntp < 4; ++ntp) {
        const int nt0 = wave * 8 + ntp * 2;
        const int nt1 = nt0 + 1;
        const f16x8* Bp0 = (const f16x8*)Wp + (size_t)(nt0 * 8) * 64 + lane;
        const f16x8* Bp1 = (const f16x8*)Wp + (size_t)(nt1 * 8) * 64 + lane;
        const float bias0 = bias[nt0*16 + rlo];
        const float bias1 = bias[nt1*16 + rlo];

        #pragma unroll 1
        for (int pc = 0; pc < P_BLK; pc += 2) {
            const int rbA = ((pc+0)*16 + rlo) * ROWB;
            const int rbB = ((pc+1)*16 + rlo) * ROWB;
            f32x4 a00 = {0.f,0.f,0.f,0.f}, a01 = {0.f,0.f,0.f,0.f};
            f32x4 a10 = {0.f,0.f,0.f,0.f}, a11 = {0.f,0.f,0.f,0.f};
            #pragma unroll
            for (int kk = 0; kk < 8; ++kk) {
                const f16x8 b0 = Bp0[kk*64];
                const f16x8 b1 = Bp1[kk*64];
                const int co = kk*64 + csub;
                const f16x8 fa0 = *(const f16x8*)(Ab + rbA + co);
                const f16x8 fa1 = *(const f16x8*)(Ab + rbB + co);
                a00 = MFMA16(fa0, b0, a00);  a01 = MFMA16(fa0, b1, a01);
                a10 = MFMA16(fa1, b0, a10);  a11 = MFMA16(fa1, b1, a11);
            }
            float v0 = fmaxf(fmaxf(a00[0], a00[1]), fmaxf(a00[2], a00[3]));
            float v1 = fmaxf(fmaxf(a01[0], a01[1]), fmaxf(a01[2], a01[3]));
            float v2 = fmaxf(fmaxf(a10[0], a10[1]), fmaxf(a10[2], a10[3]));
            float v3 = fmaxf(fmaxf(a11[0], a11[1]), fmaxf(a11[2], a11[3]));
            v0 = fmaxf(v0, __shfl_xor(v0, 16)); v0 = fmaxf(v0, __shfl_xor(v0, 32));
            v1 = fmaxf(v1, __shfl_xor(v1, 16)); v1 = fmaxf(v1, __shfl_xor(v1, 32));
            v2 = fmaxf(v2, __shfl_xor(v2, 16)); v2 = fmaxf(v2, __shfl_xor(v2, 32));
            v3 = fmaxf(v3, __shfl_xor(v3, 16)); v3 = fmaxf(v3, __shfl_xor(v3, 32));
            if (lane < 16) {
                out[(size_t)(m0 + pc + 0) * C_OUT + nt0*16 + lane] = v0 + bias0;
                out[(size_t)(m0 + pc + 0) * C_OUT + nt1*16 + lane] = v1 + bias1;
                out[(size_t)(m0 + pc + 1) * C_OUT + nt0*16 + lane] = v2 + bias0;
                out[(size_t)(m0 + pc + 1) * C_OUT + nt1*16 + lane] = v3 + bias1;
            }
        }
    }
}

extern "C" void kernel_launch(void* const* d_in, const int* in_sizes, int n_in,
                              void* d_out, int out_size, void* d_ws, size_t ws_size,
                              hipStream_t stream) {
    const float* x     = (const float*)d_in[0];
    const int*   idx   = (const int*)d_in[1];
    const float* gamma = (const float*)d_in[2];
    const float* beta  = (const float*)d_in[3];
    const float* W     = (const float*)d_in[4];
    const float* b     = (const float*)d_in[5];
    float* out = (float*)d_out;
    unsigned short* Wp = (unsigned short*)d_ws;   // 256 KiB scratch

    hipLaunchKernelGGL(pack_w_kernel, dim3((C_IN * C_OUT) / 256), dim3(256), 0, stream, W, Wp);
    hipLaunchKernelGGL(fused_gather_ln_gemm_max, dim3(M_PTS / P_BLK), dim3(NTHREADS), 0, stream,
                       x, idx, gamma, beta, Wp, b, out);
}

// Round 24
// 146.956 us; speedup vs baseline: 1.0369x; 1.0369x over previous
//
#include <hip/hip_runtime.h>

typedef _Float16 f16x8 __attribute__((ext_vector_type(8)));
typedef unsigned short ushort8 __attribute__((ext_vector_type(8)));
typedef float f32x4 __attribute__((ext_vector_type(4)));

#define C_IN     256
#define C_OUT    512
#define M_PTS    25000
#define KNN      16
#define P_BLK    4
#define ROWS     (P_BLK * KNN)   /* 64 */
#define ROWB     528             /* padded row stride in bytes (264 f16), 16B-aligned */
#define NTHREADS 256

#define MFMA16(a, b, c) __builtin_amdgcn_mfma_f32_16x16x32_f16(a, b, c, 0, 0, 0)

__device__ __forceinline__ unsigned short f2h(float f) {
    _Float16 h = (_Float16)f;
    return __builtin_bit_cast(unsigned short, h);
}

// Pack W [C_IN][C_OUT] f32 -> f16 in MFMA B-fragment order (verified):
// Wp[nt*4096 + kk*512 + lane*8 + j] = W[(kk*32 + (lane>>4)*8 + j)*C_OUT + nt*16 + (lane&15)]
__global__ void pack_w_kernel(const float* __restrict__ W, unsigned short* __restrict__ Wp) {
    int t = blockIdx.x * blockDim.x + threadIdx.x;   // 0 .. 131071
    int j    = t & 7;
    int lane = (t >> 3) & 63;
    int kk   = (t >> 9) & 7;
    int nt   = t >> 12;                               // 0..31
    int k = kk * 32 + ((lane >> 4) << 3) + j;
    int n = nt * 16 + (lane & 15);
    Wp[t] = f2h(W[k * C_OUT + n]);
}

// Champion structure (R17/R21/R23, passed 3x) with ONE change: phase-1 WRITER
// REASSIGNMENT. The A-tile byte layout is bit-identical (phase 2 verbatim);
// only which thread writes which bytes changes. Old: thread λ wrote bytes
// 32λ,32λ+16 -> banks (4r+8λ%32+d)%32 = 16 banks, 4-way conflict = the
// measured 1.44e7 SQ_LDS_BANK_CONFLICT (~56K cyc/CU = 14% of runtime).
// New: thread λ owns f16 cols [8λ,8λ+8) and [128+8λ,128+8λ+8) -> stores at
// bytes 16λ and 256+16λ -> banks (4λ+d)%32 = all 32 banks, 2 lanes/bank (free
// per m136). Gather loads become 2x32B chunks/thread (x is L3-resident; row
// bytes all consumed either way). LN math per-element identical.
__global__ __launch_bounds__(NTHREADS, 4)
void fused_gather_ln_gemm_max(const float* __restrict__ x,
                              const int* __restrict__ idx,
                              const float* __restrict__ gamma,
                              const float* __restrict__ beta,
                              const unsigned short* __restrict__ Wp,
                              const float* __restrict__ bias,
                              float* __restrict__ out) {
    __shared__ char Ab[ROWS * ROWB];   // 33 KiB, f16 A-tile, padded rows, NO swizzle

    const int tid  = threadIdx.x;
    const int lane = tid & 63;
    const int wave = tid >> 6;
    const int m0   = blockIdx.x * P_BLK;
    const int lam  = tid & 15;         // λ: column-group owner within a row

    // ---- Phase 1: gather + LayerNorm -> LDS (f16), conflict-free writes ----
    // thread λ owns f16 cols [8λ, 8λ+8) and [128+8λ, 128+8λ+8)
    float gm[16], bt[16];
    {
        const float4* gp = (const float4*)gamma;
        const float4* bp = (const float4*)beta;
        float4 g0 = gp[lam*2],     g1 = gp[lam*2 + 1];
        float4 g2 = gp[32 + lam*2], g3 = gp[32 + lam*2 + 1];
        float4 b0 = bp[lam*2],     b1 = bp[lam*2 + 1];
        float4 b2 = bp[32 + lam*2], b3 = bp[32 + lam*2 + 1];
        gm[0]=g0.x; gm[1]=g0.y; gm[2]=g0.z; gm[3]=g0.w;
        gm[4]=g1.x; gm[5]=g1.y; gm[6]=g1.z; gm[7]=g1.w;
        gm[8]=g2.x; gm[9]=g2.y; gm[10]=g2.z; gm[11]=g2.w;
        gm[12]=g3.x; gm[13]=g3.y; gm[14]=g3.z; gm[15]=g3.w;
        bt[0]=b0.x; bt[1]=b0.y; bt[2]=b0.z; bt[3]=b0.w;
        bt[4]=b1.x; bt[5]=b1.y; bt[6]=b1.z; bt[7]=b1.w;
        bt[8]=b2.x; bt[9]=b2.y; bt[10]=b2.z; bt[11]=b2.w;
        bt[12]=b3.x; bt[13]=b3.y; bt[14]=b3.z; bt[15]=b3.w;
    }
    #pragma unroll
    for (int it = 0; it < ROWS / 16; ++it) {
        const int r  = it * 16 + (tid >> 4);
        const int xr = idx[m0 * KNN + r];
        const float4* xp = (const float4*)(x + (size_t)xr * C_IN);
        float vv[16];
        {
            float4 v0 = xp[lam*2];
            float4 v1 = xp[lam*2 + 1];
            float4 v2 = xp[32 + lam*2];
            float4 v3 = xp[32 + lam*2 + 1];
            vv[0]=v0.x; vv[1]=v0.y; vv[2]=v0.z; vv[3]=v0.w;
            vv[4]=v1.x; vv[5]=v1.y; vv[6]=v1.z; vv[7]=v1.w;
            vv[8]=v2.x; vv[9]=v2.y; vv[10]=v2.z; vv[11]=v2.w;
            vv[12]=v3.x; vv[13]=v3.y; vv[14]=v3.z; vv[15]=v3.w;
        }
        float s = 0.f, sq = 0.f;
        #pragma unroll
        for (int e = 0; e < 16; ++e) { s += vv[e]; sq += vv[e]*vv[e]; }
        #pragma unroll
        for (int o = 1; o < 16; o <<= 1) {
            s  += __shfl_xor(s, o);
            sq += __shfl_xor(sq, o);
        }
        const float mu  = s * (1.0f/256.0f);
        const float var = sq * (1.0f/256.0f) - mu * mu;
        const float rs  = rsqrtf(var + 1e-5f);
        ushort8 c0, c1;
        #pragma unroll
        for (int e = 0; e < 8; ++e) c0[e] = f2h((vv[e]   - mu)*rs*gm[e]   + bt[e]);
        #pragma unroll
        for (int e = 0; e < 8; ++e) c1[e] = f2h((vv[e+8] - mu)*rs*gm[e+8] + bt[e+8]);
        // cols 8λ.. at byte 16λ; cols 128+8λ.. at byte 256+16λ  (layout unchanged)
        *(ushort8*)(Ab + r*ROWB + lam*16)       = c0;
        *(ushort8*)(Ab + r*ROWB + 256 + lam*16) = c1;
    }
    __syncthreads();

    // ---- Phase 2: kk-outer, 2-point chunks (VERBATIM champion) ----
    const int csub = (lane >> 4) << 4;
    const int rlo  = lane & 15;

    #pragma unroll 1
    for (int ntp = 0; ntp < 4; ++ntp) {
        const int nt0 = wave * 8 + ntp * 2;
        const int nt1 = nt0 + 1;
        const f16x8* Bp0 = (const f16x8*)Wp + (size_t)(nt0 * 8) * 64 + lane;
        const f16x8* Bp1 = (const f16x8*)Wp + (size_t)(nt1 * 8) * 64 + lane;
        const float bias0 = bias[nt0*16 + rlo];
        const float bias1 = bias[nt1*16 + rlo];

        #pragma unroll 1
        for (int pc = 0; pc < P_BLK; pc += 2) {
            const int rbA = ((pc+0)*16 + rlo) * ROWB;
            const int rbB = ((pc+1)*16 + rlo) * ROWB;
            f32x4 a00 = {0.f,0.f,0.f,0.f}, a01 = {0.f,0.f,0.f,0.f};
            f32x4 a10 = {0.f,0.f,0.f,0.f}, a11 = {0.f,0.f,0.f,0.f};
            #pragma unroll
            for (int kk = 0; kk < 8; ++kk) {
                const f16x8 b0 = Bp0[kk*64];
                const f16x8 b1 = Bp1[kk*64];
                const int co = kk*64 + csub;
                const f16x8 fa0 = *(const f16x8*)(Ab + rbA + co);
                const f16x8 fa1 = *(const f16x8*)(Ab + rbB + co);
                a00 = MFMA16(fa0, b0, a00);  a01 = MFMA16(fa0, b1, a01);
                a10 = MFMA16(fa1, b0, a10);  a11 = MFMA16(fa1, b1, a11);
            }
            float v0 = fmaxf(fmaxf(a00[0], a00[1]), fmaxf(a00[2], a00[3]));
            float v1 = fmaxf(fmaxf(a01[0], a01[1]), fmaxf(a01[2], a01[3]));
            float v2 = fmaxf(fmaxf(a10[0], a10[1]), fmaxf(a10[2], a10[3]));
            float v3 = fmaxf(fmaxf(a11[0], a11[1]), fmaxf(a11[2], a11[3]));
            v0 = fmaxf(v0, __shfl_xor(v0, 16)); v0 = fmaxf(v0, __shfl_xor(v0, 32));
            v1 = fmaxf(v1, __shfl_xor(v1, 16)); v1 = fmaxf(v1, __shfl_xor(v1, 32));
            v2 = fmaxf(v2, __shfl_xor(v2, 16)); v2 = fmaxf(v2, __shfl_xor(v2, 32));
            v3 = fmaxf(v3, __shfl_xor(v3, 16)); v3 = fmaxf(v3, __shfl_xor(v3, 32));
            if (lane < 16) {
                out[(size_t)(m0 + pc + 0) * C_OUT + nt0*16 + lane] = v0 + bias0;
                out[(size_t)(m0 + pc + 0) * C_OUT + nt1*16 + lane] = v1 + bias1;
                out[(size_t)(m0 + pc + 1) * C_OUT + nt0*16 + lane] = v2 + bias0;
                out[(size_t)(m0 + pc + 1) * C_OUT + nt1*16 + lane] = v3 + bias1;
            }
        }
    }
}

extern "C" void kernel_launch(void* const* d_in, const int* in_sizes, int n_in,
                              void* d_out, int out_size, void* d_ws, size_t ws_size,
                              hipStream_t stream) {
    const float* x     = (const float*)d_in[0];
    const int*   idx   = (const int*)d_in[1];
    const float* gamma = (const float*)d_in[2];
    const float* beta  = (const float*)d_in[3];
    const float* W     = (const float*)d_in[4];
    const float* b     = (const float*)d_in[5];
    float* out = (float*)d_out;
    unsigned short* Wp = (unsigned short*)d_ws;   // 256 KiB scratch

    hipLaunchKernelGGL(pack_w_kernel, dim3((C_IN * C_OUT) / 256), dim3(256), 0, stream, W, Wp);
    hipLaunchKernelGGL(fused_gather_ln_gemm_max, dim3(M_PTS / P_BLK), dim3(NTHREADS), 0, stream,
                       x, idx, gamma, beta, Wp, b, out);
}